// Round 1
// baseline (1704.437 us; speedup 1.0000x reference)
//
#include <hip/hip_runtime.h>
#include <math.h>

#define T_MAXX 128
#define BATCHN 64
#define NC     32
#define BW     16
#define BLANKC (NC - 1)
#define NEGF   (-1e30f)
#define NCAND  (BW + BW * NC)   // 528

typedef unsigned long long u64;

static const u64 PA_C = 0x100000001B3ULL;          // FNV prime
static const u64 PB_C = 6364136223846793005ULL;    // LCG multiplier

// Correctly-rounded f32 transcendentals via double (closest match to host libm)
__device__ __forceinline__ float xexp(float x)  { return (float)exp((double)x); }
__device__ __forceinline__ float xlog(float x)  { return (float)log((double)x); }
__device__ __forceinline__ float xlog1p(float x){ return (float)log1p((double)x); }

// jnp.logaddexp: amax + log1p(exp(-|a-b|))
__device__ __forceinline__ float logaddexpf_(float a, float b) {
    float m = fmaxf(a, b);
    float d = fabsf(a - b);
    return m + xlog1p(xexp(-d));
}

extern "C" __global__ void __launch_bounds__(64)
CTCPredictionsCpu_kernel(const float* __restrict__ data,
                         const int* __restrict__ dlen,
                         int* __restrict__ out)
{
    const int b   = blockIdx.x;
    const int tid = threadIdx.x;
    const int length = dlen[b];

    __shared__ float xsh[NC];
    __shared__ float logp[NC];
    __shared__ float ext[BW][NC];             // candidate scores, row-major = flat idx i*32+c
    __shared__ unsigned char consumed[BW][NC];
    __shared__ float lpB[BW], lpNB[BW], lpTot[BW];
    __shared__ float stayB[BW], stayNB[BW], stayScore[BW];
    __shared__ int   lens[BW], lastch[BW], validv[BW];
    __shared__ u64   hA[BW], hB[BW];
    __shared__ int   trace[T_MAXX][BW];       // src | char<<8 | is_ext<<16
    __shared__ int   outbuf[T_MAXX];

    if (tid < BW) {
        lens[tid]   = 0;
        lastch[tid] = -1;
        lpB[tid]    = (tid == 0) ? 0.0f : NEGF;
        lpNB[tid]   = NEGF;
        hA[tid]     = 1;
        hB[tid]     = 1;
    }
    __syncthreads();

    for (int t = 0; t < length; ++t) {
        // ---- log_softmax over classes (serial, mimics x-m then -log(sum)) ----
        if (tid < NC) xsh[tid] = data[((size_t)t * BATCHN + b) * NC + tid];
        __syncthreads();
        if (tid == 0) {
            float m = xsh[0];
            for (int c = 1; c < NC; ++c) m = fmaxf(m, xsh[c]);
            float s = 0.0f;
            for (int c = 0; c < NC; ++c) s += xexp(xsh[c] - m);
            float ls = xlog(s);
            for (int c = 0; c < NC; ++c) logp[c] = (xsh[c] - m) - ls;
        }
        __syncthreads();

        // ---- per-beam stay candidates ----
        if (tid < BW) {
            float a  = lpB[tid], nb = lpNB[tid];
            float tot = logaddexpf_(a, nb);
            lpTot[tid]  = tot;
            validv[tid] = (tot > -5e29f) ? 1 : 0;
            stayB[tid]  = tot + logp[BLANKC];
            stayNB[tid] = (lens[tid] > 0) ? (nb + logp[lastch[tid]]) : NEGF;
        }
        __syncthreads();

        // ---- ext candidates: ext[i][c] ----
        #pragma unroll
        for (int r = 0; r < 8; ++r) {
            int e = tid + (r << 6);
            int i = e >> 5, c = e & 31;
            float base = (c == lastch[i]) ? lpB[i] : lpTot[i];
            float v = base + logp[c];
            if (c == BLANKC) v = NEGF;
            ext[i][c] = v;
            consumed[i][c] = 0;
        }
        __syncthreads();

        // ---- merge ext(i,c) into stay(j) when seq_j == seq_i ++ [c] ----
        if (tid < BW) {
            const int j = tid;
            float merged = NEGF;
            if (validv[j]) {
                const int lj = lens[j];
                const int cj = lastch[j];
                const u64 tA = hA[j], tB = hB[j];
                const u64 addA = (u64)(cj + 1), addB = (u64)(cj + 1);
                // pass 1: max + mark consumed
                float mm = NEGF; int nm = 0;
                for (int i = 0; i < BW; ++i) {
                    if (lens[i] + 1 == lj &&
                        tA == hA[i] * PA_C + addA &&
                        tB == hB[i] * PB_C + addB) {
                        float v = ext[i][cj];
                        mm = fmaxf(mm, v);
                        consumed[i][cj] = 1;
                        ++nm;
                    }
                }
                if (nm > 0) {
                    // pass 2: sum of exp(v - mm)  (non-matched NEG entries underflow to 0)
                    float s = 0.0f;
                    for (int i = 0; i < BW; ++i) {
                        if (lens[i] + 1 == lj &&
                            tA == hA[i] * PA_C + addA &&
                            tB == hB[i] * PB_C + addB) {
                            s += xexp(ext[i][cj] - mm);
                        }
                    }
                    merged = mm + xlog(s);
                }
            }
            float snb = logaddexpf_(stayNB[j], merged);
            stayNB[j] = snb;
            stayScore[j] = logaddexpf_(stayB[j], snb);
        }
        __syncthreads();

        // ---- mask consumed ext entries ----
        #pragma unroll
        for (int r = 0; r < 8; ++r) {
            int e = tid + (r << 6);
            int i = e >> 5, c = e & 31;
            if (consumed[i][c]) ext[i][c] = NEGF;
        }
        __syncthreads();

        // ---- top-16 of 528 with jax tie-break (lower index wins on ties) ----
        u64 keys[9];
        const float* extflat = &ext[0][0];
        #pragma unroll
        for (int r = 0; r < 9; ++r) {
            int idx = tid + (r << 6);
            u64 key = 0;
            if (idx < NCAND) {
                float sc = (idx < BW) ? stayScore[idx] : extflat[idx - BW];
                unsigned u = __float_as_uint(sc);
                u = (u & 0x80000000u) ? ~u : (u | 0x80000000u);
                key = ((u64)u << 32) | (u64)(0xFFFFFFFFu - (unsigned)idx);
            }
            keys[r] = key;
        }
        int myidx = 0;
        #pragma unroll 1
        for (int k = 0; k < BW; ++k) {
            u64 best = keys[0];
            #pragma unroll
            for (int r = 1; r < 9; ++r) best = (keys[r] > best) ? keys[r] : best;
            #pragma unroll
            for (int off = 1; off < 64; off <<= 1) {
                u64 o = __shfl_xor(best, off);
                best = (o > best) ? o : best;
            }
            if (tid == k) myidx = (int)(0xFFFFFFFFu - (unsigned)(best & 0xFFFFFFFFu));
            #pragma unroll
            for (int r = 0; r < 9; ++r) if (keys[r] == best) keys[r] = 0;
        }

        // ---- state update (read old state into regs, sync, write) ----
        int nlen = 0, nlast = 0, trc = 0;
        float nb_ = 0.0f, nnb_ = 0.0f;
        u64 nA = 0, nB = 0;
        if (tid < BW) {
            int idx = myidx;
            bool isext = idx >= BW;
            int istay = (idx < BW) ? idx : (BW - 1);
            int e = isext ? (idx - BW) : 0;
            int ie = e >> 5, ce = e & 31;
            int src = isext ? ie : istay;
            nlen  = lens[src] + (isext ? 1 : 0);
            nb_   = isext ? NEGF : stayB[istay];
            nnb_  = isext ? ext[ie][ce] : stayNB[istay];
            nlast = isext ? ce : lastch[src];
            nA    = isext ? (hA[src] * PA_C + (u64)(ce + 1)) : hA[src];
            nB    = isext ? (hB[src] * PB_C + (u64)(ce + 1)) : hB[src];
            trc   = src | (ce << 8) | (isext ? (1 << 16) : 0);
        }
        __syncthreads();
        if (tid < BW) {
            lens[tid] = nlen;  lpB[tid] = nb_;  lpNB[tid] = nnb_;
            lastch[tid] = nlast; hA[tid] = nA;  hB[tid] = nB;
            trace[t][tid] = trc;
        }
        __syncthreads();
    }

    // ---- backtrack beam 0 to dense output (padded with BLANK_PAD = 0) ----
    for (int l = tid; l < T_MAXX; l += 64) outbuf[l] = 0;
    __syncthreads();
    if (tid == 0) {
        int cur = 0;
        int pos = lens[0] - 1;
        for (int s = length - 1; s >= 0; --s) {
            int e = trace[s][cur];
            if (e & (1 << 16)) outbuf[pos--] = (e >> 8) & 0xFF;
            cur = e & 0xFF;
        }
    }
    __syncthreads();
    for (int l = tid; l < T_MAXX; l += 64) out[b * T_MAXX + l] = outbuf[l];
}

extern "C" void kernel_launch(void* const* d_in, const int* in_sizes, int n_in,
                              void* d_out, int out_size, void* d_ws, size_t ws_size,
                              hipStream_t stream) {
    const float* data = (const float*)d_in[0];
    const int*   dlen = (const int*)d_in[1];
    int*         out  = (int*)d_out;
    hipLaunchKernelGGL(CTCPredictionsCpu_kernel, dim3(BATCHN), dim3(64), 0, stream,
                       data, dlen, out);
}

// Round 3
// 1410.081 us; speedup vs baseline: 1.2088x; 1.2088x over previous
//
#include <hip/hip_runtime.h>
#include <math.h>

#define T_MAXX 128
#define BATCHN 64
#define NC     32
#define BW     16
#define BLANKC (NC - 1)
#define NEGF   (-1e30f)
#define NCAND  (BW + BW * NC)   // 528

typedef unsigned long long u64;

static const u64 PA_C = 0x100000001B3ULL;          // FNV prime
static const u64 PB_C = 6364136223846793005ULL;    // LCG multiplier

// Accurate f32 transcendentals (ocml, ~1 ulp — same class as XLA/Eigen ref)
__device__ __forceinline__ float xexp(float x)  { return expf(x); }
__device__ __forceinline__ float xlog(float x)  { return logf(x); }
__device__ __forceinline__ float xlog1p(float x){ return log1pf(x); }

// jnp.logaddexp: max + log1p(exp(-|a-b|))
__device__ __forceinline__ float logaddexpf_(float a, float b) {
    float m = fmaxf(a, b);
    float d = fabsf(a - b);
    return m + xlog1p(xexp(-d));
}

extern "C" __global__ void __launch_bounds__(64)
CTCPredictionsCpu_kernel(const float* __restrict__ data,
                         const int* __restrict__ dlen,
                         int* __restrict__ out)
{
    const int b   = blockIdx.x;
    const int tid = threadIdx.x;
    const int length = dlen[b];

    __shared__ float logp[NC];
    __shared__ float ext[BW][NC];             // candidate scores, flat idx i*32+c
    __shared__ unsigned char consumed[BW][NC];
    __shared__ float lpB[BW], lpNB[BW], lpTot[BW];
    __shared__ float stayB[BW], stayNB[BW], stayScore[BW];
    __shared__ int   lens[BW], lastch[BW], validv[BW];
    __shared__ u64   hA[BW], hB[BW];
    __shared__ int   trace[T_MAXX][BW];       // src | char<<8 | is_ext<<16
    __shared__ int   outbuf[T_MAXX];

    if (tid < BW) {
        lens[tid]   = 0;
        lastch[tid] = -1;
        lpB[tid]    = (tid == 0) ? 0.0f : NEGF;
        lpNB[tid]   = NEGF;
        hA[tid]     = 1;
        hB[tid]     = 1;
    }
    __syncthreads();

    // software-pipelined frame load (128 B/step)
    float xcur = (tid < NC && length > 0) ? data[(size_t)b * NC + tid] : 0.0f;

    for (int t = 0; t < length; ++t) {
        // issue next frame's load early; it drains under this step's compute
        float xnext = (tid < NC && t + 1 < length)
                        ? data[((size_t)(t + 1) * BATCHN + b) * NC + tid] : 0.0f;

        // ---- wave-parallel log_softmax (uniform shift -> rankings invariant) ----
        float x = xcur;
        float m = x;
        #pragma unroll
        for (int off = 16; off >= 1; off >>= 1) m = fmaxf(m, __shfl_xor(m, off, 32));
        float e = (tid < NC) ? xexp(x - m) : 0.0f;
        float s = e;
        #pragma unroll
        for (int off = 16; off >= 1; off >>= 1) s += __shfl_xor(s, off, 32);
        float ls = xlog(s);
        if (tid < NC) logp[tid] = (x - m) - ls;
        __syncthreads();

        // ---- per-beam stay candidates ----
        if (tid < BW) {
            float a  = lpB[tid], nb = lpNB[tid];
            float tot = logaddexpf_(a, nb);
            lpTot[tid]  = tot;
            validv[tid] = (tot > -5e29f) ? 1 : 0;
            stayB[tid]  = tot + logp[BLANKC];
            stayNB[tid] = (lens[tid] > 0) ? (nb + logp[lastch[tid]]) : NEGF;
        }
        __syncthreads();

        // ---- ext candidates: ext[i][c] ----
        #pragma unroll
        for (int r = 0; r < 8; ++r) {
            int ei = tid + (r << 6);
            int i = ei >> 5, c = ei & 31;
            float base = (c == lastch[i]) ? lpB[i] : lpTot[i];
            float v = base + logp[c];
            if (c == BLANKC) v = NEGF;
            ext[i][c] = v;
            consumed[i][c] = 0;
        }
        __syncthreads();

        // ---- merge ext(i,c) into stay(j) when seq_j == seq_i ++ [c] ----
        if (tid < BW) {
            const int j = tid;
            float merged = NEGF;
            if (validv[j]) {
                const int lj = lens[j];
                const int cj = lastch[j];
                const u64 tA = hA[j], tB = hB[j];
                const u64 addv = (u64)(cj + 1);
                float mm = NEGF; int nm = 0;
                for (int i = 0; i < BW; ++i) {
                    if (lens[i] + 1 == lj &&
                        tA == hA[i] * PA_C + addv &&
                        tB == hB[i] * PB_C + addv) {
                        mm = fmaxf(mm, ext[i][cj]);
                        consumed[i][cj] = 1;
                        ++nm;
                    }
                }
                if (nm > 0) {
                    float ssum = 0.0f;
                    for (int i = 0; i < BW; ++i) {
                        if (lens[i] + 1 == lj &&
                            tA == hA[i] * PA_C + addv &&
                            tB == hB[i] * PB_C + addv) {
                            ssum += xexp(ext[i][cj] - mm);
                        }
                    }
                    merged = mm + xlog(ssum);
                }
            }
            float snb = logaddexpf_(stayNB[j], merged);
            stayNB[j] = snb;
            stayScore[j] = logaddexpf_(stayB[j], snb);
        }
        __syncthreads();

        // ---- mask consumed ext entries ----
        #pragma unroll
        for (int r = 0; r < 8; ++r) {
            int ei = tid + (r << 6);
            int i = ei >> 5, c = ei & 31;
            if (consumed[i][c]) ext[i][c] = NEGF;
        }
        __syncthreads();

        // ---- top-16 of 528 with jax tie-break (lower index wins on ties) ----
        u64 keys[9];
        const float* extflat = &ext[0][0];
        #pragma unroll
        for (int r = 0; r < 9; ++r) {
            int idx = tid + (r << 6);
            u64 key = 0;
            if (idx < NCAND) {
                float sc = (idx < BW) ? stayScore[idx] : extflat[idx - BW];
                unsigned u = __float_as_uint(sc);
                u = (u & 0x80000000u) ? ~u : (u | 0x80000000u);
                key = ((u64)u << 32) | (u64)(0xFFFFFFFFu - (unsigned)idx);
            }
            keys[r] = key;
        }
        int myidx = 0;
        #pragma unroll 1
        for (int k = 0; k < BW; ++k) {
            u64 best = keys[0];
            #pragma unroll
            for (int r = 1; r < 9; ++r) best = (keys[r] > best) ? keys[r] : best;
            #pragma unroll
            for (int off = 1; off < 64; off <<= 1) {
                u64 o = __shfl_xor(best, off);
                best = (o > best) ? o : best;
            }
            if (tid == k) myidx = (int)(0xFFFFFFFFu - (unsigned)(best & 0xFFFFFFFFu));
            #pragma unroll
            for (int r = 0; r < 9; ++r) if (keys[r] == best) keys[r] = 0;
        }

        // ---- state update (read old state into regs, sync, write) ----
        int nlen = 0, nlast = 0, trc = 0;
        float nb_ = 0.0f, nnb_ = 0.0f;
        u64 nA = 0, nB = 0;
        if (tid < BW) {
            int idx = myidx;
            bool isext = idx >= BW;
            int istay = (idx < BW) ? idx : (BW - 1);
            int ei = isext ? (idx - BW) : 0;
            int ie = ei >> 5, ce = ei & 31;
            int src = isext ? ie : istay;
            nlen  = lens[src] + (isext ? 1 : 0);
            nb_   = isext ? NEGF : stayB[istay];
            nnb_  = isext ? ext[ie][ce] : stayNB[istay];
            nlast = isext ? ce : lastch[src];
            nA    = isext ? (hA[src] * PA_C + (u64)(ce + 1)) : hA[src];
            nB    = isext ? (hB[src] * PB_C + (u64)(ce + 1)) : hB[src];
            trc   = src | (ce << 8) | (isext ? (1 << 16) : 0);
        }
        __syncthreads();
        if (tid < BW) {
            lens[tid] = nlen;  lpB[tid] = nb_;  lpNB[tid] = nnb_;
            lastch[tid] = nlast; hA[tid] = nA;  hB[tid] = nB;
            trace[t][tid] = trc;
        }
        __syncthreads();

        xcur = xnext;
    }

    // ---- backtrack beam 0 to dense output (padded with BLANK_PAD = 0) ----
    for (int l = tid; l < T_MAXX; l += 64) outbuf[l] = 0;
    __syncthreads();
    if (tid == 0) {
        int cur = 0;
        int pos = lens[0] - 1;
        for (int s = length - 1; s >= 0; --s) {
            int e = trace[s][cur];
            if (e & (1 << 16)) outbuf[pos--] = (e >> 8) & 0xFF;
            cur = e & 0xFF;
        }
    }
    __syncthreads();
    for (int l = tid; l < T_MAXX; l += 64) out[b * T_MAXX + l] = outbuf[l];
}

extern "C" void kernel_launch(void* const* d_in, const int* in_sizes, int n_in,
                              void* d_out, int out_size, void* d_ws, size_t ws_size,
                              hipStream_t stream) {
    const float* data = (const float*)d_in[0];
    const int*   dlen = (const int*)d_in[1];
    int*         out  = (int*)d_out;
    hipLaunchKernelGGL(CTCPredictionsCpu_kernel, dim3(BATCHN), dim3(64), 0, stream,
                       data, dlen, out);
}